// Round 3
// baseline (793.293 us; speedup 1.0000x reference)
//
#include <hip/hip_runtime.h>
#include <hip/hip_bf16.h>
#include <math.h>

#define NN 100000
#define NE 3200000
#define NF 512
#define NTILE 6250   // NN/16 exactly
#define NB 782       // ceil(NN/128) buckets of 128 nodes
#define NCH 256      // edge chunks
#define CHUNK 12500  // NE/NCH exactly
#define HSZ (NB * NCH)   // 200192 (dst hist)
#define HSZ2 (2 * HSZ)   // 400384 (dst hist + src hist)
#define NSB1 ((HSZ2 + 1023) / 1024)  // 391
#define APAD 17          // LDS accumulator row stride (bank-conflict pad)

typedef __attribute__((ext_vector_type(8))) short short8;
typedef __attribute__((ext_vector_type(4))) float f32x4;

__device__ inline unsigned bf16_rne(float f) {
    unsigned u = __builtin_bit_cast(unsigned, f);
    return (u + 0x7FFFu + ((u >> 16) & 1u)) >> 16;
}
__device__ inline float bf16_back(unsigned h) {
    return __builtin_bit_cast(float, h << 16);
}

// -------- per-chunk bucket histogram for BOTH keys (LDS, no global atomics) ----
// hist[0..HSZ)        : dst-keyed counts
// hist[HSZ..2*HSZ)    : src-keyed counts
__global__ __launch_bounds__(256) void k_hist(const int* __restrict__ src,
                                              const int* __restrict__ dst,
                                              int* __restrict__ hist) {
    __shared__ int lcntD[NB];
    __shared__ int lcntS[NB];
    for (int i = threadIdx.x; i < NB; i += 256) { lcntD[i] = 0; lcntS[i] = 0; }
    __syncthreads();
    const int e0 = blockIdx.x * CHUNK;
    for (int i = threadIdx.x; i < CHUNK; i += 256) {
        atomicAdd(&lcntD[dst[e0 + i] >> 7], 1);
        atomicAdd(&lcntS[src[e0 + i] >> 7], 1);
    }
    __syncthreads();
    for (int b = threadIdx.x; b < NB; b += 256) {
        hist[b * NCH + blockIdx.x] = lcntD[b];
        hist[HSZ + b * NCH + blockIdx.x] = lcntS[b];
    }
}

// ---------------- 3-kernel exclusive scan of hist[0..HSZ2) (in place) ---------
// Joint scan: src-region offsets automatically start at NE (total of dst counts),
// which is exactly where the src-copy lives in the shared `packed` buffer.
__global__ __launch_bounds__(1024) void k_scan1(int* __restrict__ hist,
                                                int* __restrict__ bsum) {
    __shared__ int tmp[2][1024];
    int tid = threadIdx.x;
    int i = blockIdx.x * 1024 + tid;
    int v = (i < HSZ2) ? hist[i] : 0;
    int pp = 0;
    tmp[0][tid] = v;
    __syncthreads();
    for (int off = 1; off < 1024; off <<= 1) {
        int t = tmp[pp][tid];
        if (tid >= off) t += tmp[pp][tid - off];
        tmp[1 - pp][tid] = t;
        __syncthreads();
        pp = 1 - pp;
    }
    int incl = tmp[pp][tid];
    if (i < HSZ2) hist[i] = incl - v;  // exclusive, sans block offset
    if (tid == 1023) bsum[blockIdx.x] = incl;
}

__global__ __launch_bounds__(512) void k_scan2(int* __restrict__ bsum) {
    __shared__ int tmp[2][512];
    int tid = threadIdx.x;
    int v = (tid < NSB1) ? bsum[tid] : 0;
    int pp = 0;
    tmp[0][tid] = v;
    __syncthreads();
    for (int off = 1; off < 512; off <<= 1) {
        int t = tmp[pp][tid];
        if (tid >= off) t += tmp[pp][tid - off];
        tmp[1 - pp][tid] = t;
        __syncthreads();
        pp = 1 - pp;
    }
    if (tid < NSB1) bsum[tid] = tmp[pp][tid] - v;  // exclusive
}

__global__ __launch_bounds__(256) void k_scan3(int* __restrict__ hist,
                                               const int* __restrict__ bsum,
                                               float* __restrict__ tbuf) {
    int i = blockIdx.x * 256 + threadIdx.x;
    if (i < HSZ2) hist[i] += bsum[i >> 10];
    if (i == 0) hist[HSZ2] = 2 * NE;  // end sentinel for last src bucket
    if (i < 16) tbuf[i] = 0.0f;       // zero pooled accumulator
    // note: hist[HSZ] == NE automatically (scan total of dst region)
}

// -------- placement of BOTH copies: LDS cursors, zero global atomics ----------
// packed[0..NE)      : dst-bucketed, payload = ((dst&127)<<17) | src
// packed[NE..2*NE)   : src-bucketed, payload = ((src&127)<<17) | dst
__global__ __launch_bounds__(256) void k_place2(const int* __restrict__ src,
                                                const int* __restrict__ dst,
                                                const int* __restrict__ hist,
                                                unsigned* __restrict__ packed) {
    __shared__ int sbD[NB];
    __shared__ int lcD[NB];
    __shared__ int sbS[NB];
    __shared__ int lcS[NB];
    const int c = blockIdx.x;
    for (int b = threadIdx.x; b < NB; b += 256) {
        sbD[b] = hist[b * NCH + c];
        lcD[b] = 0;
        sbS[b] = hist[HSZ + b * NCH + c];
        lcS[b] = 0;
    }
    __syncthreads();
    const int e0 = c * CHUNK;
    for (int i = threadIdx.x; i < CHUNK; i += 256) {
        int d = dst[e0 + i];
        int s = src[e0 + i];
        int bd = d >> 7;
        int pd = atomicAdd(&lcD[bd], 1);
        packed[sbD[bd] + pd] = ((unsigned)(d & 127) << 17) | (unsigned)s;
        int bs = s >> 7;
        int ps = atomicAdd(&lcS[bs], 1);
        packed[sbS[bs] + ps] = ((unsigned)(s & 127) << 17) | (unsigned)d;
    }
}

// -------- per-node in-degree -> dinv, from unsorted dst buckets ---------------
__global__ __launch_bounds__(256) void k_deg(const unsigned* __restrict__ packed,
                                             const int* __restrict__ hist,
                                             float* __restrict__ dinv) {
    __shared__ int cnt[128];
    const int tid = threadIdx.x;
    const int b = blockIdx.x;
    if (tid < 128) cnt[tid] = 0;
    __syncthreads();
    const int beg = hist[b * NCH], end = hist[(b + 1) * NCH];
    for (int i = beg + tid; i < end; i += 256)
        atomicAdd(&cnt[packed[i] >> 17], 1);
    __syncthreads();
    const int n = b * 128 + tid;
    if (tid < 128 && n < NN) dinv[n] = rsqrtf((float)cnt[tid] + 1.0f);
}

// -------- column sums of A-hat: cacc[s] = sum_{edges s->d} dinv[d] ------------
// per src-bucket LDS accumulation over the src-bucketed copy; no sort needed.
__global__ __launch_bounds__(256) void k_csum(const unsigned* __restrict__ packed,
                                              const int* __restrict__ hist,
                                              const float* __restrict__ dinv,
                                              float* __restrict__ cacc) {
    __shared__ float sums[128];
    const int tid = threadIdx.x;
    const int b = blockIdx.x;
    if (tid < 128) sums[tid] = 0.0f;
    __syncthreads();
    const int beg = hist[HSZ + b * NCH], end = hist[HSZ + (b + 1) * NCH];
    for (int i = beg + tid; i < end; i += 256) {
        unsigned p = packed[i];
        atomicAdd(&sums[p >> 17], dinv[p & 0x1FFFFu]);
    }
    __syncthreads();
    const int n = b * 128 + tid;
    if (tid < 128 && n < NN) cacc[n] = sums[tid];
}

// ---------------- GEMM1 via MFMA 16x16x32 bf16, split hi/lo ----------------
// Writes hs[n][c] = dinv[n] * (x@W1)[n][c]
__global__ __launch_bounds__(256) void k_gemm1(
    const float* __restrict__ x, const float* __restrict__ W1,
    const float* __restrict__ dinv, float* __restrict__ hs) {
    __shared__ short8 Bh[1024];  // idx = (kk*4+q)*16 + c
    __shared__ short8 Bl[1024];

    const int t = threadIdx.x;
    {   // stage W: thread (c,q,kk0) handles kk = kk0*4+i
        const int c = t & 15, q = (t >> 4) & 3, kk0 = t >> 6;
        for (int i = 0; i < 4; ++i) {
            const int kk = kk0 * 4 + i;
            short8 hi, lo;
#pragma unroll
            for (int j = 0; j < 8; ++j) {
                float w = W1[(kk * 32 + q * 8 + j) * 16 + c];
                unsigned h = bf16_rne(w);
                float back = bf16_back(h);
                unsigned l = bf16_rne(w - back);
                hi[j] = (short)h;
                lo[j] = (short)l;
            }
            Bh[(kk * 4 + q) * 16 + c] = hi;
            Bl[(kk * 4 + q) * 16 + c] = lo;
        }
    }
    __syncthreads();

    const int lane = t & 63;
    const int wave = blockIdx.x * 4 + (t >> 6);
    if (wave >= NTILE) return;
    const int nb = wave * 16;
    const int m = lane & 15;  // A row within tile AND B/C col (channel)
    const int q = lane >> 4;

    const float4* xrow = (const float4*)(x + (size_t)(nb + m) * NF + q * 8);
    float4 xr[32];
#pragma unroll
    for (int kk = 0; kk < 16; ++kk) {
        xr[2 * kk] = xrow[kk * 8];
        xr[2 * kk + 1] = xrow[kk * 8 + 1];
    }

    f32x4 acc = {0.f, 0.f, 0.f, 0.f};
#pragma unroll
    for (int kk = 0; kk < 16; ++kk) {
        float f[8] = {xr[2 * kk].x,     xr[2 * kk].y,     xr[2 * kk].z,
                      xr[2 * kk].w,     xr[2 * kk + 1].x, xr[2 * kk + 1].y,
                      xr[2 * kk + 1].z, xr[2 * kk + 1].w};
        short8 ah, al;
#pragma unroll
        for (int j = 0; j < 8; ++j) {
            unsigned h = bf16_rne(f[j]);
            ah[j] = (short)h;
            al[j] = (short)bf16_rne(f[j] - bf16_back(h));
        }
        short8 bh = Bh[(kk * 4 + q) * 16 + m];
        short8 bl = Bl[(kk * 4 + q) * 16 + m];
        acc = __builtin_amdgcn_mfma_f32_16x16x32_bf16(ah, bh, acc, 0, 0, 0);
        acc = __builtin_amdgcn_mfma_f32_16x16x32_bf16(ah, bl, acc, 0, 0, 0);
        acc = __builtin_amdgcn_mfma_f32_16x16x32_bf16(al, bh, acc, 0, 0, 0);
    }

    // C/D: col=lane&15, row=q*4+reg
#pragma unroll
    for (int r = 0; r < 4; ++r) {
        const int n = nb + q * 4 + r;
        hs[n * 16 + m] = dinv[n] * acc[r];
    }
}

// -------- scatter-accumulate + fused finalize/pool, one block per dst bucket --
// LDS acc[128][16] (pad 17): acc[d][:] += hs[src][:] per edge (unsorted bucket).
// Then t_partial[c] = sum_n w[n]*relu(dinv[n]*(acc[n][c]+hs[n][c])+b1[c]),
// w[n] = dinv[n]*(cacc[n]+dinv[n]); one 16-float atomic add per block.
__global__ __launch_bounds__(256) void k_scatter(
    const unsigned* __restrict__ packed, const int* __restrict__ hist,
    const float* __restrict__ hs, const float* __restrict__ dinv,
    const float* __restrict__ cacc, const float* __restrict__ b1,
    float* __restrict__ tbuf) {
    __shared__ float acc[128 * APAD];
    __shared__ float red[4][16];
    const int tid = threadIdx.x;
    const int b = blockIdx.x;
    for (int i = tid; i < 128 * APAD; i += 256) acc[i] = 0.0f;
    __syncthreads();
    const int beg = hist[b * NCH], end = hist[(b + 1) * NCH];
    const int e = tid >> 2;  // edge slot 0..63
    const int q = tid & 3;   // channel quad
    int i = beg + e;
    for (; i + 64 < end; i += 128) {  // 2 edges per slot per iter -> 32 rows/wave in flight
        unsigned p0 = packed[i];
        unsigned p1 = packed[i + 64];
        const float4 v0 = *(const float4*)(hs + (size_t)(p0 & 0x1FFFFu) * 16 + q * 4);
        const float4 v1 = *(const float4*)(hs + (size_t)(p1 & 0x1FFFFu) * 16 + q * 4);
        float* a0 = &acc[(p0 >> 17) * APAD + q * 4];
        atomicAdd(a0 + 0, v0.x);
        atomicAdd(a0 + 1, v0.y);
        atomicAdd(a0 + 2, v0.z);
        atomicAdd(a0 + 3, v0.w);
        float* a1 = &acc[(p1 >> 17) * APAD + q * 4];
        atomicAdd(a1 + 0, v1.x);
        atomicAdd(a1 + 1, v1.y);
        atomicAdd(a1 + 2, v1.z);
        atomicAdd(a1 + 3, v1.w);
    }
    if (i < end) {
        unsigned p0 = packed[i];
        const float4 v0 = *(const float4*)(hs + (size_t)(p0 & 0x1FFFFu) * 16 + q * 4);
        float* a0 = &acc[(p0 >> 17) * APAD + q * 4];
        atomicAdd(a0 + 0, v0.x);
        atomicAdd(a0 + 1, v0.y);
        atomicAdd(a0 + 2, v0.z);
        atomicAdd(a0 + 3, v0.w);
    }
    __syncthreads();
    // finalize + pooled partial
    const int c = tid & 15;
    const int rr = tid >> 4;  // 0..15
    const float b1c = b1[c];
    float s = 0.0f;
#pragma unroll
    for (int k = 0; k < 8; ++k) {
        const int r = rr + 16 * k;
        const int n = b * 128 + r;
        if (n < NN) {
            const float dn = dinv[n];
            const float o = dn * (acc[r * APAD + c] + hs[n * 16 + c]);
            const float w = dn * (cacc[n] + dn);
            s += w * fmaxf(o + b1c, 0.0f);
        }
    }
    s += __shfl_xor(s, 16, 64);
    s += __shfl_xor(s, 32, 64);
    const int wid = tid >> 6;
    const int lane = tid & 63;
    if (lane < 16) red[wid][lane] = s;
    __syncthreads();
    if (tid < 16) {
        float tot = red[0][tid] + red[1][tid] + red[2][tid] + red[3][tid];
        atomicAdd(&tbuf[tid], tot);
    }
}

// ---------------- finalize: pooled = (t @ W2)/N + b2, then softmax ------------
__global__ void k_softmax(const float* __restrict__ tbuf, const float* __restrict__ W2,
                          const float* __restrict__ b2, float* __restrict__ out) {
    __shared__ float tv[16];
    __shared__ float vals[16];
    int k = threadIdx.x;
    if (k < 16) tv[k] = tbuf[k];
    __syncthreads();
    if (k < 16) {
        float acc = 0.0f;
        for (int c = 0; c < 16; ++c) acc += tv[c] * W2[c * 16 + k];
        vals[k] = acc * (1.0f / NN) + b2[k];
    }
    __syncthreads();
    if (k < 16) {
        float m = -INFINITY;
        for (int i = 0; i < 16; ++i) m = fmaxf(m, vals[i]);
        float sum = 0.0f;
        for (int i = 0; i < 16; ++i) sum += expf(vals[i] - m);
        out[k] = expf(vals[k] - m) / sum;
    }
}

extern "C" void kernel_launch(void* const* d_in, const int* in_sizes, int n_in,
                              void* d_out, int out_size, void* d_ws, size_t ws_size,
                              hipStream_t stream) {
    const float* x = (const float*)d_in[0];
    const int* edge = (const int*)d_in[1];
    const float* W1 = (const float*)d_in[2];
    const float* b1 = (const float*)d_in[3];
    const float* W2 = (const float*)d_in[4];
    const float* b2 = (const float*)d_in[5];
    const int* src = edge;
    const int* dst = edge + NE;

    // layout (int units); hs kept 16B aligned
    char* ws = (char*)d_ws;
    int* hist = (int*)ws;                             // HSZ2+1 (pad to 400388)
    int* bsum = hist + 400388;                        // 512
    unsigned* packed = (unsigned*)(bsum + 512);       // 2*NE
    float* dinv = (float*)(packed + 2 * NE);          // NN
    float* hs = dinv + NN;                            // NN*16 (16B aligned)
    float* cacc = hs + (size_t)NN * 16;               // NN
    float* tbuf = cacc + NN;                          // 16

    float* out = (float*)d_out;

    k_hist<<<NCH, 256, 0, stream>>>(src, dst, hist);
    k_scan1<<<NSB1, 1024, 0, stream>>>(hist, bsum);
    k_scan2<<<1, 512, 0, stream>>>(bsum);
    k_scan3<<<HSZ2 / 256, 256, 0, stream>>>(hist, bsum, tbuf);
    k_place2<<<NCH, 256, 0, stream>>>(src, dst, hist, packed);
    k_deg<<<NB, 256, 0, stream>>>(packed, hist, dinv);
    k_csum<<<NB, 256, 0, stream>>>(packed, hist, dinv, cacc);

    k_gemm1<<<(NTILE + 3) / 4, 256, 0, stream>>>(x, W1, dinv, hs);
    k_scatter<<<NB, 256, 0, stream>>>(packed, hist, hs, dinv, cacc, b1, tbuf);
    k_softmax<<<1, 64, 0, stream>>>(tbuf, W2, b2, out);
}

// Round 4
// 587.582 us; speedup vs baseline: 1.3501x; 1.3501x over previous
//
#include <hip/hip_runtime.h>
#include <hip/hip_bf16.h>
#include <math.h>

#define NN 100000
#define NE 3200000
#define NF 512
#define NTILE 6250    // NN/16 exactly
#define NBK 196       // buckets of 512 nodes per key (196*512 = 100352 >= NN)
#define NBK2 392      // both keys
#define NCH 256       // edge chunks
#define CHUNK 12500   // NE/NCH exactly

typedef __attribute__((ext_vector_type(8))) short short8;
typedef __attribute__((ext_vector_type(4))) float f32x4;

__device__ inline unsigned bf16_rne(float f) {
    unsigned u = __builtin_bit_cast(unsigned, f);
    return (u + 0x7FFFu + ((u >> 16) & 1u)) >> 16;
}
__device__ inline float bf16_back(unsigned h) {
    return __builtin_bit_cast(float, h << 16);
}

// ---------------- zero the reservation counters ----------------
__global__ __launch_bounds__(512) void k_zero(int* __restrict__ gcount) {
    if (threadIdx.x < NBK2) gcount[threadIdx.x] = 0;
}

// -------- per-chunk LDS hist + global reservation (atomic-return) -------------
// boff[c*NBK2 + b] = start of chunk c's entries within bucket b's segment
__global__ __launch_bounds__(256) void k_hist(const int* __restrict__ src,
                                              const int* __restrict__ dst,
                                              int* __restrict__ gcount,
                                              int* __restrict__ boff) {
    __shared__ int lcnt[NBK2];
    for (int i = threadIdx.x; i < NBK2; i += 256) lcnt[i] = 0;
    __syncthreads();
    const int e0 = blockIdx.x * CHUNK;
    for (int i = threadIdx.x; i < CHUNK; i += 256) {
        atomicAdd(&lcnt[dst[e0 + i] >> 9], 1);
        atomicAdd(&lcnt[NBK + (src[e0 + i] >> 9)], 1);
    }
    __syncthreads();
    // rotate start bucket per block to spread same-address atomic contention
    const int rot = blockIdx.x % NBK2;
    for (int k = threadIdx.x; k < NBK2; k += 256) {
        int b = k + rot;
        if (b >= NBK2) b -= NBK2;
        int c = lcnt[b];
        boff[blockIdx.x * NBK2 + b] = atomicAdd(&gcount[b], c);
    }
}

// -------- exclusive scan of 392 bucket totals -> gbase[393] -------------------
// joint scan: src-key buckets (196..391) start at NE automatically.
__global__ __launch_bounds__(512) void k_base(const int* __restrict__ gcount,
                                              int* __restrict__ gbase) {
    __shared__ int tmp[2][512];
    int tid = threadIdx.x;
    int v = (tid < NBK2) ? gcount[tid] : 0;
    int pp = 0;
    tmp[0][tid] = v;
    __syncthreads();
    for (int off = 1; off < 512; off <<= 1) {
        int t = tmp[pp][tid];
        if (tid >= off) t += tmp[pp][tid - off];
        tmp[1 - pp][tid] = t;
        __syncthreads();
        pp = 1 - pp;
    }
    int incl = tmp[pp][tid];
    if (tid < NBK2) gbase[tid] = incl - v;
    if (tid == NBK2 - 1) gbase[NBK2] = incl;  // = 2*NE
}

// -------- placement of BOTH copies: LDS cursors, coalesced-ish runs -----------
// packed[0..NE)      : dst-bucketed, payload = ((dst&511)<<17) | src
// packed[NE..2*NE)   : src-bucketed, payload = ((src&511)<<17) | dst
__global__ __launch_bounds__(256) void k_place(const int* __restrict__ src,
                                               const int* __restrict__ dst,
                                               const int* __restrict__ gbase,
                                               const int* __restrict__ boff,
                                               unsigned* __restrict__ packed) {
    __shared__ int sbase[NBK2];
    __shared__ int lcur[NBK2];
    const int c = blockIdx.x;
    for (int b = threadIdx.x; b < NBK2; b += 256) {
        sbase[b] = gbase[b] + boff[c * NBK2 + b];
        lcur[b] = 0;
    }
    __syncthreads();
    const int e0 = c * CHUNK;
    for (int i = threadIdx.x; i < CHUNK; i += 256) {
        int d = dst[e0 + i];
        int s = src[e0 + i];
        int bd = d >> 9;
        int pd = atomicAdd(&lcur[bd], 1);
        packed[sbase[bd] + pd] = ((unsigned)(d & 511) << 17) | (unsigned)s;
        int bs = NBK + (s >> 9);
        int ps = atomicAdd(&lcur[bs], 1);
        packed[sbase[bs] + ps] = ((unsigned)(s & 511) << 17) | (unsigned)d;
    }
}

// -------- per-bucket counting sort -> csr (separate buffer) + dinv ------------
// two streaming passes over the bucket; no LDS staging, no in-place race.
__global__ __launch_bounds__(512) void k_bsort(const unsigned* __restrict__ packed,
                                               const int* __restrict__ gbase,
                                               int* __restrict__ csr,
                                               int* __restrict__ row_start,
                                               float* __restrict__ dinv) {
    __shared__ int cnt[512];
    __shared__ int tmp[2][512];
    const int tid = threadIdx.x;
    const int b = blockIdx.x;
    const int beg = gbase[b], end = gbase[b + 1];
    cnt[tid] = 0;
    __syncthreads();
    for (int i = beg + tid; i < end; i += 512)
        atomicAdd(&cnt[packed[i] >> 17], 1);
    __syncthreads();
    int v = cnt[tid];
    int pp = 0;
    tmp[0][tid] = v;
    __syncthreads();
    for (int off = 1; off < 512; off <<= 1) {
        int t = tmp[pp][tid];
        if (tid >= off) t += tmp[pp][tid - off];
        tmp[1 - pp][tid] = t;
        __syncthreads();
        pp = 1 - pp;
    }
    int excl = tmp[pp][tid] - v;
    int n = b * 512 + tid;
    if (n <= NN) {
        if (n < NN) dinv[n] = rsqrtf((float)v + 1.0f);
        row_start[n] = beg + excl;  // n==NN lands at beg+sz == NE (bucket 195)
    }
    cnt[tid] = excl;  // reuse as cursor
    __syncthreads();
    for (int i = beg + tid; i < end; i += 512) {
        unsigned p = packed[i];
        int pos = atomicAdd(&cnt[p >> 17], 1);
        csr[beg + pos] = (int)(p & 0x1FFFFu);
    }
}

// -------- column sums of A-hat: cacc[s] = sum_{edges s->d} dinv[d] ------------
__global__ __launch_bounds__(512) void k_csum(const unsigned* __restrict__ packed,
                                              const int* __restrict__ gbase,
                                              const float* __restrict__ dinv,
                                              float* __restrict__ cacc) {
    __shared__ float sums[512];
    const int tid = threadIdx.x;
    const int b = blockIdx.x;
    sums[tid] = 0.0f;
    __syncthreads();
    const int beg = gbase[NBK + b], end = gbase[NBK + b + 1];
    for (int i = beg + tid; i < end; i += 512) {
        unsigned p = packed[i];
        atomicAdd(&sums[p >> 17], dinv[p & 0x1FFFFu]);
    }
    __syncthreads();
    const int n = b * 512 + tid;
    if (n < NN) cacc[n] = sums[tid];
}

// ---------------- GEMM1 via MFMA 16x16x32 bf16, split hi/lo ----------------
// Writes hs[n][c] = dinv[n] * (x@W1)[n][c]
__global__ __launch_bounds__(256) void k_gemm1(
    const float* __restrict__ x, const float* __restrict__ W1,
    const float* __restrict__ dinv, float* __restrict__ hs) {
    __shared__ short8 Bh[1024];  // idx = (kk*4+q)*16 + c
    __shared__ short8 Bl[1024];

    const int t = threadIdx.x;
    {   // stage W: thread (c,q,kk0) handles kk = kk0*4+i
        const int c = t & 15, q = (t >> 4) & 3, kk0 = t >> 6;
        for (int i = 0; i < 4; ++i) {
            const int kk = kk0 * 4 + i;
            short8 hi, lo;
#pragma unroll
            for (int j = 0; j < 8; ++j) {
                float w = W1[(kk * 32 + q * 8 + j) * 16 + c];
                unsigned h = bf16_rne(w);
                float back = bf16_back(h);
                unsigned l = bf16_rne(w - back);
                hi[j] = (short)h;
                lo[j] = (short)l;
            }
            Bh[(kk * 4 + q) * 16 + c] = hi;
            Bl[(kk * 4 + q) * 16 + c] = lo;
        }
    }
    __syncthreads();

    const int lane = t & 63;
    const int wave = blockIdx.x * 4 + (t >> 6);
    if (wave >= NTILE) return;
    const int nb = wave * 16;
    const int m = lane & 15;  // A row within tile AND B/C col (channel)
    const int q = lane >> 4;

    const float4* xrow = (const float4*)(x + (size_t)(nb + m) * NF + q * 8);
    float4 xr[32];
#pragma unroll
    for (int kk = 0; kk < 16; ++kk) {
        xr[2 * kk] = xrow[kk * 8];
        xr[2 * kk + 1] = xrow[kk * 8 + 1];
    }

    f32x4 acc = {0.f, 0.f, 0.f, 0.f};
#pragma unroll
    for (int kk = 0; kk < 16; ++kk) {
        float f[8] = {xr[2 * kk].x,     xr[2 * kk].y,     xr[2 * kk].z,
                      xr[2 * kk].w,     xr[2 * kk + 1].x, xr[2 * kk + 1].y,
                      xr[2 * kk + 1].z, xr[2 * kk + 1].w};
        short8 ah, al;
#pragma unroll
        for (int j = 0; j < 8; ++j) {
            unsigned h = bf16_rne(f[j]);
            ah[j] = (short)h;
            al[j] = (short)bf16_rne(f[j] - bf16_back(h));
        }
        short8 bh = Bh[(kk * 4 + q) * 16 + m];
        short8 bl = Bl[(kk * 4 + q) * 16 + m];
        acc = __builtin_amdgcn_mfma_f32_16x16x32_bf16(ah, bh, acc, 0, 0, 0);
        acc = __builtin_amdgcn_mfma_f32_16x16x32_bf16(ah, bl, acc, 0, 0, 0);
        acc = __builtin_amdgcn_mfma_f32_16x16x32_bf16(al, bh, acc, 0, 0, 0);
    }

    // C/D: col=lane&15, row=q*4+reg
#pragma unroll
    for (int r = 0; r < 4; ++r) {
        const int n = nb + q * 4 + r;
        hs[n * 16 + m] = dinv[n] * acc[r];
    }
}

// -------- gather + fused layer-2 finalize/pool --------------------------------
// wave handles 4 nodes; per node: a1 = dinv*(sum_{s in N(n)} hs[s] + hs[n]);
// pooled partial += w[n]*relu(a1+b1), w[n] = dinv[n]*(cacc[n]+dinv[n]).
// Block writes one 16-float partial to pblock (no atomics).
__global__ __launch_bounds__(256) void k_gather(
    const float* __restrict__ hs, const float* __restrict__ dinv,
    const int* __restrict__ row_start, const int* __restrict__ csr,
    const float* __restrict__ cacc, const float* __restrict__ b1,
    float* __restrict__ pblock) {
    const int lane = threadIdx.x & 63;
    const int wid = threadIdx.x >> 6;
    const int e = lane >> 2;  // edge slot 0..15
    const int q = lane & 3;   // channel quad 0..3
    const float4 b1v = ((const float4*)b1)[q];
    float p0 = 0.f, p1 = 0.f, p2 = 0.f, p3 = 0.f;  // pooled partial (lanes<4)
#pragma unroll
    for (int j = 0; j < 4; ++j) {
        const int n = blockIdx.x * 16 + wid * 4 + j;
        const int beg = row_start[n], end = row_start[n + 1];
        float a0 = 0.f, a1 = 0.f, a2 = 0.f, a3 = 0.f;
        int i = beg + e;
        for (; i + 16 < end; i += 32) {  // 2 rows per slot in flight
            int s0 = csr[i];
            int s1 = csr[i + 16];
            const float4 v0 = *(const float4*)(hs + (size_t)s0 * 16 + q * 4);
            const float4 v1 = *(const float4*)(hs + (size_t)s1 * 16 + q * 4);
            a0 += v0.x + v1.x;
            a1 += v0.y + v1.y;
            a2 += v0.z + v1.z;
            a3 += v0.w + v1.w;
        }
        if (i < end) {
            const float4 v = *(const float4*)(hs + (size_t)csr[i] * 16 + q * 4);
            a0 += v.x; a1 += v.y; a2 += v.z; a3 += v.w;
        }
        for (int m = 4; m < 64; m <<= 1) {
            a0 += __shfl_xor(a0, m, 64);
            a1 += __shfl_xor(a1, m, 64);
            a2 += __shfl_xor(a2, m, 64);
            a3 += __shfl_xor(a3, m, 64);
        }
        if (lane < 4) {  // lane == q
            const float dn = dinv[n];
            const float4 hv = *(const float4*)(hs + (size_t)n * 16 + lane * 4);
            const float w = dn * (cacc[n] + dn);
            p0 += w * fmaxf(dn * (a0 + hv.x) + b1v.x, 0.f);
            p1 += w * fmaxf(dn * (a1 + hv.y) + b1v.y, 0.f);
            p2 += w * fmaxf(dn * (a2 + hv.z) + b1v.z, 0.f);
            p3 += w * fmaxf(dn * (a3 + hv.w) + b1v.w, 0.f);
        }
    }
    __shared__ float red[4][16];
    if (lane < 4) {
        red[wid][lane * 4 + 0] = p0;
        red[wid][lane * 4 + 1] = p1;
        red[wid][lane * 4 + 2] = p2;
        red[wid][lane * 4 + 3] = p3;
    }
    __syncthreads();
    if (threadIdx.x < 16) {
        pblock[blockIdx.x * 16 + threadIdx.x] =
            red[0][threadIdx.x] + red[1][threadIdx.x] +
            red[2][threadIdx.x] + red[3][threadIdx.x];
    }
}

// -------- reduce pblock, then pooled = (t @ W2)/N + b2, softmax ---------------
__global__ __launch_bounds__(256) void k_softmax(const float* __restrict__ pblock,
                                                 const float* __restrict__ W2,
                                                 const float* __restrict__ b2,
                                                 float* __restrict__ out) {
    __shared__ float red[16][16];
    const int tid = threadIdx.x;
    const int c = tid & 15;
    const int r = tid >> 4;
    float s = 0.0f;
    for (int i = r; i < NTILE; i += 16) s += pblock[i * 16 + c];
    red[r][c] = s;
    __syncthreads();
    __shared__ float tv[16];
    __shared__ float vals[16];
    if (tid < 16) {
        float tot = 0.0f;
        for (int i = 0; i < 16; ++i) tot += red[i][tid];
        tv[tid] = tot;
    }
    __syncthreads();
    if (tid < 16) {
        float acc = 0.0f;
        for (int cc = 0; cc < 16; ++cc) acc += tv[cc] * W2[cc * 16 + tid];
        vals[tid] = acc * (1.0f / NN) + b2[tid];
    }
    __syncthreads();
    if (tid < 16) {
        float m = -INFINITY;
        for (int i = 0; i < 16; ++i) m = fmaxf(m, vals[i]);
        float sum = 0.0f;
        for (int i = 0; i < 16; ++i) sum += expf(vals[i] - m);
        out[tid] = expf(vals[tid] - m) / sum;
    }
}

extern "C" void kernel_launch(void* const* d_in, const int* in_sizes, int n_in,
                              void* d_out, int out_size, void* d_ws, size_t ws_size,
                              hipStream_t stream) {
    const float* x = (const float*)d_in[0];
    const int* edge = (const int*)d_in[1];
    const float* W1 = (const float*)d_in[2];
    const float* b1 = (const float*)d_in[3];
    const float* W2 = (const float*)d_in[4];
    const float* b2 = (const float*)d_in[5];
    const int* src = edge;
    const int* dst = edge + NE;

    // workspace layout (int units); hs 16B-aligned
    char* ws = (char*)d_ws;
    int* gcount = (int*)ws;                        // 400
    int* gbase = gcount + 400;                     // 400 (needs NBK2+1=393)
    int* boff = gbase + 400;                       // 256*392 = 100352
    unsigned* packed = (unsigned*)(boff + 100352); // 2*NE
    int* csr = (int*)(packed + 2 * NE);            // NE
    int* row_start = csr + NE;                     // NN+1 -> pad 100004
    float* dinv = (float*)(row_start + 100004);    // NN
    float* hs = dinv + NN;                         // NN*16 (16B aligned)
    float* cacc = hs + (size_t)NN * 16;            // NN
    float* pblock = cacc + NN;                     // NTILE*16 = 100000

    float* out = (float*)d_out;

    k_zero<<<1, 512, 0, stream>>>(gcount);
    k_hist<<<NCH, 256, 0, stream>>>(src, dst, gcount, boff);
    k_base<<<1, 512, 0, stream>>>(gcount, gbase);
    k_place<<<NCH, 256, 0, stream>>>(src, dst, gbase, boff, packed);
    k_bsort<<<NBK, 512, 0, stream>>>(packed, gbase, csr, row_start, dinv);
    k_csum<<<NBK, 512, 0, stream>>>(packed, gbase, dinv, cacc);
    k_gemm1<<<(NTILE + 3) / 4, 256, 0, stream>>>(x, W1, dinv, hs);
    k_gather<<<NTILE, 256, 0, stream>>>(hs, dinv, row_start, csr, cacc, b1, pblock);
    k_softmax<<<1, 256, 0, stream>>>(pblock, W2, b2, out);
}

// Round 5
// 543.890 us; speedup vs baseline: 1.4586x; 1.0803x over previous
//
#include <hip/hip_runtime.h>
#include <hip/hip_bf16.h>
#include <math.h>

#define NN 100000
#define NE 3200000
#define NF 512
#define NTILE 6250    // NN/16 exactly
#define NB 782        // 128-node buckets per key (782*128 = 100096 >= NN)
#define NB2 1564      // both keys
#define NCH 256       // edge chunks
#define CHUNK 12500   // NE/NCH exactly
#define BCAP 8192     // LDS staging capacity (bucket avg 4093, ~64 sigma margin)
#define GBLK 2048     // gather blocks
#define GW (GBLK * 4) // gather waves

typedef __attribute__((ext_vector_type(8))) short short8;
typedef __attribute__((ext_vector_type(4))) float f32x4;

__device__ inline unsigned bf16_rne(float f) {
    unsigned u = __builtin_bit_cast(unsigned, f);
    return (u + 0x7FFFu + ((u >> 16) & 1u)) >> 16;
}
__device__ inline float bf16_back(unsigned h) {
    return __builtin_bit_cast(float, h << 16);
}

// ---------------- zero the reservation counters ----------------
__global__ __launch_bounds__(1024) void k_zero(int* __restrict__ gcount) {
    int i = threadIdx.x;
    if (i < NB2) gcount[i] = 0;
    if (i + 1024 < NB2) gcount[i + 1024] = 0;
}

// -------- per-chunk LDS hist + global reservation (atomic-return) -------------
// boff[c*NB2 + b] = start of chunk c's entries within bucket b's segment
__global__ __launch_bounds__(256) void k_hist(const int* __restrict__ src,
                                              const int* __restrict__ dst,
                                              int* __restrict__ gcount,
                                              int* __restrict__ boff) {
    __shared__ int lcnt[NB2];
    for (int i = threadIdx.x; i < NB2; i += 256) lcnt[i] = 0;
    __syncthreads();
    const int e0 = blockIdx.x * CHUNK;
    for (int i = threadIdx.x; i < CHUNK; i += 256) {
        atomicAdd(&lcnt[dst[e0 + i] >> 7], 1);
        atomicAdd(&lcnt[NB + (src[e0 + i] >> 7)], 1);
    }
    __syncthreads();
    // rotate start bucket per block to spread same-address atomic contention
    const int rot = (blockIdx.x * 61) % NB2;
    for (int k = threadIdx.x; k < NB2; k += 256) {
        int b = k + rot;
        if (b >= NB2) b -= NB2;
        boff[blockIdx.x * NB2 + b] = atomicAdd(&gcount[b], lcnt[b]);
    }
}

// -------- exclusive scan of 1564 bucket totals -> gbase[NB2+1] ----------------
// joint scan: src-key buckets (NB..NB2) start at NE automatically.
__global__ __launch_bounds__(512) void k_base(const int* __restrict__ gcount,
                                              int* __restrict__ gbase) {
    __shared__ int tmp[2][512];
    const int tid = threadIdx.x;
    int v[4];
    int s = 0;
    const int base = tid * 4;
#pragma unroll
    for (int k = 0; k < 4; ++k) {
        const int idx = base + k;
        v[k] = (idx < NB2) ? gcount[idx] : 0;
        s += v[k];
    }
    int pp = 0;
    tmp[0][tid] = s;
    __syncthreads();
    for (int off = 1; off < 512; off <<= 1) {
        int t = tmp[pp][tid];
        if (tid >= off) t += tmp[pp][tid - off];
        tmp[1 - pp][tid] = t;
        __syncthreads();
        pp = 1 - pp;
    }
    int run = tmp[pp][tid] - s;  // exclusive prefix of this thread's 4-segment
#pragma unroll
    for (int k = 0; k < 4; ++k) {
        const int idx = base + k;
        if (idx <= NB2) gbase[idx] = run;  // idx==NB2 gets total = 2*NE
        run += v[k];
    }
}

// -------- placement of BOTH copies: LDS cursors, zero global atomics ----------
// packed[0..NE)      : dst-bucketed, payload = ((dst&127)<<17) | src
// packed[NE..2*NE)   : src-bucketed, payload = ((src&127)<<17) | dst
__global__ __launch_bounds__(256) void k_place(const int* __restrict__ src,
                                               const int* __restrict__ dst,
                                               const int* __restrict__ gbase,
                                               const int* __restrict__ boff,
                                               unsigned* __restrict__ packed) {
    __shared__ int sbase[NB2];
    __shared__ int lcur[NB2];
    const int c = blockIdx.x;
    for (int b = threadIdx.x; b < NB2; b += 256) {
        sbase[b] = gbase[b] + boff[c * NB2 + b];
        lcur[b] = 0;
    }
    __syncthreads();
    const int e0 = c * CHUNK;
    for (int i = threadIdx.x; i < CHUNK; i += 256) {
        int d = dst[e0 + i];
        int s = src[e0 + i];
        int bd = d >> 7;
        int pd = atomicAdd(&lcur[bd], 1);
        packed[sbase[bd] + pd] = ((unsigned)(d & 127) << 17) | (unsigned)s;
        int bs = NB + (s >> 7);
        int ps = atomicAdd(&lcur[bs], 1);
        packed[sbase[bs] + ps] = ((unsigned)(s & 127) << 17) | (unsigned)d;
    }
}

// ---------------- per-bucket counting sort -> node CSR (+dinv), in place ------
__global__ __launch_bounds__(256) void k_bsort(unsigned* __restrict__ packed,
                                               const int* __restrict__ gbase,
                                               int* __restrict__ row_start,
                                               float* __restrict__ dinv) {
    __shared__ unsigned stage[BCAP];
    __shared__ int cnt[128];
    __shared__ int t0[128], t1[128];
    const int tid = threadIdx.x;
    const int b = blockIdx.x;
    const int beg = gbase[b], end = gbase[b + 1];
    const int sz = end - beg;
    if (tid < 128) cnt[tid] = 0;
    __syncthreads();
    for (int i = tid; i < sz; i += 256) {
        unsigned p = packed[beg + i];
        if (i < BCAP) stage[i] = p;
        atomicAdd(&cnt[p >> 17], 1);
    }
    __syncthreads();
    // inclusive Hillis-Steele scan over 128 counts
    if (tid < 128) t0[tid] = cnt[tid];
    __syncthreads();
    int pp = 0;
    for (int off = 1; off < 128; off <<= 1) {
        if (tid < 128) {
            int t = (pp ? t1[tid] : t0[tid]);
            if (tid >= off) t += (pp ? t1[tid - off] : t0[tid - off]);
            if (pp) t0[tid] = t; else t1[tid] = t;
        }
        __syncthreads();
        pp = 1 - pp;
    }
    if (tid < 128) {
        int incl = pp ? t1[tid] : t0[tid];
        int excl = incl - cnt[tid];
        int n = b * 128 + tid;
        if (n < NN) {
            row_start[n] = beg + excl;
            dinv[n] = rsqrtf((float)cnt[tid] + 1.0f);
        }
        cnt[tid] = excl;  // reuse as cursor
    }
    __syncthreads();
    for (int i = tid; i < sz; i += 256) {
        unsigned p = (i < BCAP) ? stage[i] : packed[beg + i];
        int k = p >> 17;
        int pos = atomicAdd(&cnt[k], 1);
        packed[beg + pos] = p & 0x1FFFFu;
    }
    if (b == NB - 1 && tid == 0) row_start[NN] = NE;
}

// -------- column sums of A-hat: cacc[s] = sum_{edges s->d} dinv[d] ------------
__global__ __launch_bounds__(256) void k_csum(const unsigned* __restrict__ packed,
                                              const int* __restrict__ gbase,
                                              const float* __restrict__ dinv,
                                              float* __restrict__ cacc) {
    __shared__ float sums[128];
    const int tid = threadIdx.x;
    const int b = blockIdx.x;
    if (tid < 128) sums[tid] = 0.0f;
    __syncthreads();
    const int beg = gbase[NB + b], end = gbase[NB + b + 1];
    for (int i = beg + tid; i < end; i += 256) {
        unsigned p = packed[i];
        atomicAdd(&sums[p >> 17], dinv[p & 0x1FFFFu]);
    }
    __syncthreads();
    const int n = b * 128 + tid;
    if (tid < 128 && n < NN) cacc[n] = sums[tid];
}

// ---------------- GEMM1 via MFMA 16x16x32 bf16, split hi/lo ----------------
// Writes hs[n][c] = dinv[n] * (x@W1)[n][c]
__global__ __launch_bounds__(256) void k_gemm1(
    const float* __restrict__ x, const float* __restrict__ W1,
    const float* __restrict__ dinv, float* __restrict__ hs) {
    __shared__ short8 Bh[1024];  // idx = (kk*4+q)*16 + c
    __shared__ short8 Bl[1024];

    const int t = threadIdx.x;
    {   // stage W: thread (c,q,kk0) handles kk = kk0*4+i
        const int c = t & 15, q = (t >> 4) & 3, kk0 = t >> 6;
        for (int i = 0; i < 4; ++i) {
            const int kk = kk0 * 4 + i;
            short8 hi, lo;
#pragma unroll
            for (int j = 0; j < 8; ++j) {
                float w = W1[(kk * 32 + q * 8 + j) * 16 + c];
                unsigned h = bf16_rne(w);
                float back = bf16_back(h);
                unsigned l = bf16_rne(w - back);
                hi[j] = (short)h;
                lo[j] = (short)l;
            }
            Bh[(kk * 4 + q) * 16 + c] = hi;
            Bl[(kk * 4 + q) * 16 + c] = lo;
        }
    }
    __syncthreads();

    const int lane = t & 63;
    const int wave = blockIdx.x * 4 + (t >> 6);
    if (wave >= NTILE) return;
    const int nb = wave * 16;
    const int m = lane & 15;  // A row within tile AND B/C col (channel)
    const int q = lane >> 4;

    const float4* xrow = (const float4*)(x + (size_t)(nb + m) * NF + q * 8);
    float4 xr[32];
#pragma unroll
    for (int kk = 0; kk < 16; ++kk) {
        xr[2 * kk] = xrow[kk * 8];
        xr[2 * kk + 1] = xrow[kk * 8 + 1];
    }

    f32x4 acc = {0.f, 0.f, 0.f, 0.f};
#pragma unroll
    for (int kk = 0; kk < 16; ++kk) {
        float f[8] = {xr[2 * kk].x,     xr[2 * kk].y,     xr[2 * kk].z,
                      xr[2 * kk].w,     xr[2 * kk + 1].x, xr[2 * kk + 1].y,
                      xr[2 * kk + 1].z, xr[2 * kk + 1].w};
        short8 ah, al;
#pragma unroll
        for (int j = 0; j < 8; ++j) {
            unsigned h = bf16_rne(f[j]);
            ah[j] = (short)h;
            al[j] = (short)bf16_rne(f[j] - bf16_back(h));
        }
        short8 bh = Bh[(kk * 4 + q) * 16 + m];
        short8 bl = Bl[(kk * 4 + q) * 16 + m];
        acc = __builtin_amdgcn_mfma_f32_16x16x32_bf16(ah, bh, acc, 0, 0, 0);
        acc = __builtin_amdgcn_mfma_f32_16x16x32_bf16(ah, bl, acc, 0, 0, 0);
        acc = __builtin_amdgcn_mfma_f32_16x16x32_bf16(al, bh, acc, 0, 0, 0);
    }

    // C/D: col=lane&15, row=q*4+reg
#pragma unroll
    for (int r = 0; r < 4; ++r) {
        const int n = nb + q * 4 + r;
        hs[n * 16 + m] = dinv[n] * acc[r];
    }
}

// -------- gather + fused layer-2 finalize/pool (grid-stride) ------------------
// wave w handles nodes n = w, w+GW, ...; per node:
//   a1 = dinv[n]*(sum_{s in N(n)} hs[s] + hs[n])
//   pooled partial += w[n]*relu(a1+b1), w[n] = dinv[n]*(cacc[n]+dinv[n])
// Block writes one 16-float partial to pblock (no atomics).
__global__ __launch_bounds__(256) void k_gather(
    const float* __restrict__ hs, const float* __restrict__ dinv,
    const int* __restrict__ row_start, const int* __restrict__ csr,
    const float* __restrict__ cacc, const float* __restrict__ b1,
    float* __restrict__ pblock) {
    const int lane = threadIdx.x & 63;
    const int wid = threadIdx.x >> 6;
    const int w0 = blockIdx.x * 4 + wid;
    const int e = lane >> 2;  // edge slot 0..15
    const int q = lane & 3;   // channel quad 0..3
    const float4 b1v = ((const float4*)b1)[q];
    float p0 = 0.f, p1 = 0.f, p2 = 0.f, p3 = 0.f;  // pooled partial (lanes<4)
    for (int n = w0; n < NN; n += GW) {
        const int beg = row_start[n], end = row_start[n + 1];
        float a0 = 0.f, a1 = 0.f, a2 = 0.f, a3 = 0.f;
        int i = beg + e;
        for (; i + 16 < end; i += 32) {  // 2 rows per slot in flight
            int s0 = csr[i];
            int s1 = csr[i + 16];
            const float4 v0 = *(const float4*)(hs + (size_t)s0 * 16 + q * 4);
            const float4 v1 = *(const float4*)(hs + (size_t)s1 * 16 + q * 4);
            a0 += v0.x + v1.x;
            a1 += v0.y + v1.y;
            a2 += v0.z + v1.z;
            a3 += v0.w + v1.w;
        }
        if (i < end) {
            const float4 v = *(const float4*)(hs + (size_t)csr[i] * 16 + q * 4);
            a0 += v.x; a1 += v.y; a2 += v.z; a3 += v.w;
        }
        for (int m = 4; m < 64; m <<= 1) {
            a0 += __shfl_xor(a0, m, 64);
            a1 += __shfl_xor(a1, m, 64);
            a2 += __shfl_xor(a2, m, 64);
            a3 += __shfl_xor(a3, m, 64);
        }
        if (lane < 4) {  // lane == q
            const float dn = dinv[n];
            const float4 hv = *(const float4*)(hs + (size_t)n * 16 + lane * 4);
            const float ww = dn * (cacc[n] + dn);
            p0 += ww * fmaxf(dn * (a0 + hv.x) + b1v.x, 0.f);
            p1 += ww * fmaxf(dn * (a1 + hv.y) + b1v.y, 0.f);
            p2 += ww * fmaxf(dn * (a2 + hv.z) + b1v.z, 0.f);
            p3 += ww * fmaxf(dn * (a3 + hv.w) + b1v.w, 0.f);
        }
    }
    __shared__ float red[4][16];
    if (lane < 4) {
        red[wid][lane * 4 + 0] = p0;
        red[wid][lane * 4 + 1] = p1;
        red[wid][lane * 4 + 2] = p2;
        red[wid][lane * 4 + 3] = p3;
    }
    __syncthreads();
    if (threadIdx.x < 16) {
        pblock[blockIdx.x * 16 + threadIdx.x] =
            red[0][threadIdx.x] + red[1][threadIdx.x] +
            red[2][threadIdx.x] + red[3][threadIdx.x];
    }
}

// -------- reduce pblock, then pooled = (t @ W2)/N + b2, softmax ---------------
__global__ __launch_bounds__(256) void k_softmax(const float* __restrict__ pblock,
                                                 const float* __restrict__ W2,
                                                 const float* __restrict__ b2,
                                                 float* __restrict__ out) {
    __shared__ float red[16][16];
    const int tid = threadIdx.x;
    const int c = tid & 15;
    const int r = tid >> 4;
    float s = 0.0f;
    for (int i = r; i < GBLK; i += 16) s += pblock[i * 16 + c];
    red[r][c] = s;
    __syncthreads();
    __shared__ float tv[16];
    __shared__ float vals[16];
    if (tid < 16) {
        float tot = 0.0f;
        for (int i = 0; i < 16; ++i) tot += red[i][tid];
        tv[tid] = tot;
    }
    __syncthreads();
    if (tid < 16) {
        float acc = 0.0f;
        for (int cc = 0; cc < 16; ++cc) acc += tv[cc] * W2[cc * 16 + tid];
        vals[tid] = acc * (1.0f / NN) + b2[tid];
    }
    __syncthreads();
    if (tid < 16) {
        float m = -INFINITY;
        for (int i = 0; i < 16; ++i) m = fmaxf(m, vals[i]);
        float sum = 0.0f;
        for (int i = 0; i < 16; ++i) sum += expf(vals[i] - m);
        out[tid] = expf(vals[tid] - m) / sum;
    }
}

extern "C" void kernel_launch(void* const* d_in, const int* in_sizes, int n_in,
                              void* d_out, int out_size, void* d_ws, size_t ws_size,
                              hipStream_t stream) {
    const float* x = (const float*)d_in[0];
    const int* edge = (const int*)d_in[1];
    const float* W1 = (const float*)d_in[2];
    const float* b1 = (const float*)d_in[3];
    const float* W2 = (const float*)d_in[4];
    const float* b2 = (const float*)d_in[5];
    const int* src = edge;
    const int* dst = edge + NE;

    // workspace layout (int units); hs 16B-aligned
    char* ws = (char*)d_ws;
    int* gcount = (int*)ws;                        // NB2 -> pad 1600
    int* gbase = gcount + 1600;                    // NB2+1 -> pad 1600
    int* boff = gbase + 1600;                      // NCH*NB2 = 400384
    unsigned* packed = (unsigned*)(boff + 400384); // 2*NE (first NE becomes csr)
    int* row_start = (int*)(packed + 2 * NE);      // NN+1 -> pad 100004
    float* dinv = (float*)(row_start + 100004);    // NN
    float* hs = dinv + NN;                         // NN*16 (16B aligned)
    float* cacc = hs + (size_t)NN * 16;            // NN
    float* pblock = cacc + NN;                     // GBLK*16

    float* out = (float*)d_out;
    const int* csr = (const int*)packed;

    k_zero<<<1, 1024, 0, stream>>>(gcount);
    k_hist<<<NCH, 256, 0, stream>>>(src, dst, gcount, boff);
    k_base<<<1, 512, 0, stream>>>(gcount, gbase);
    k_place<<<NCH, 256, 0, stream>>>(src, dst, gbase, boff, packed);
    k_bsort<<<NB, 256, 0, stream>>>(packed, gbase, row_start, dinv);
    k_csum<<<NB, 256, 0, stream>>>(packed, gbase, dinv, cacc);
    k_gemm1<<<(NTILE + 3) / 4, 256, 0, stream>>>(x, W1, dinv, hs);
    k_gather<<<GBLK, 256, 0, stream>>>(hs, dinv, row_start, csr, cacc, b1, pblock);
    k_softmax<<<1, 256, 0, stream>>>(pblock, W2, b2, out);
}